// Round 5
// baseline (530.231 us; speedup 1.0000x reference)
//
#include <hip/hip_runtime.h>
#include <math.h>

#define T_    4
#define B_    32
#define C_    64
#define CO_   64
#define N_    4096
#define K_    8
#define PL_   3
#define TB_   128          // T_*B_
#define TN_   256          // n-tile per conv block
#define NT_   16           // N_/TN_
#define NBLK_ 2048         // TB_*NT_
#define CCH_  16           // ci chunk staged in LDS (16 is the proven optimum; 32 regressed R8)

typedef float v2f __attribute__((ext_vector_type(2)));
typedef float v4f __attribute__((ext_vector_type(4)));

#define AS1 __attribute__((address_space(1)))
#define AS3 __attribute__((address_space(3)))

// ---------------------------------------------------------------------------
// Kernel 0: repack weights into co-pairs (R2 verbatim). Required: the packed
// conv codegen (wpk + pk-fma) eliminates LDS bank conflicts and ~40us of
// VALU time vs scalar-LDS weights.
// ---------------------------------------------------------------------------
__global__ __launch_bounds__(256)
void pack_w_kernel(const float* __restrict__ w, v2f* __restrict__ wpk)
{
    int i = blockIdx.x * 256 + threadIdx.x;      // p*512 + ci*8 + k
    if (i < 32 * C_ * K_) {
        int p = i >> 9;
        int r = i & 511;
        v2f v = { w[(size_t)(2 * p) * (C_ * K_) + r],
                  w[(size_t)(2 * p + 1) * (C_ * K_) + r] };
        wpk[i] = v;
    }
}

// ---------------------------------------------------------------------------
// Kernel 1: conv + BN partials. R2-frozen staging (double-buffered xs +
// global_load_lds interior + T14 halo split, one barrier per chunk).
// THIS ROUND: ci2 loop unrolled 4x with fully static indices (manual
// rotating prefetch from R4 removed — compiler CSE'd it away, VGPR stayed
// 24). Unrolling turns the 3 ds_read_b128/iter into offset-immediate reads
// off one base register and lets the scheduler pipeline loads across
// iterations with counted lgkmcnt instead of a per-iteration drain.
// FMA order per ci2 unchanged -> y/psum bitwise identical.
// ---------------------------------------------------------------------------
__global__ __launch_bounds__(1024, 8)
void conv_stats_kernel(const float* __restrict__ x, const v2f* __restrict__ wpk,
                       float* __restrict__ y, float* __restrict__ psum)
{
    __shared__ float xs[2][CCH_][TN_ + 8];   // 2 x 16 x 264 floats = 33.8 KB

    const int bx   = blockIdx.x;
    const int tb   = bx >> 4;           // 0..127
    const int n0   = (bx & 15) * TN_;   // n tile origin
    const int tid  = threadIdx.x;
    const int lane = tid & 63;
    const int wv   = __builtin_amdgcn_readfirstlane(tid >> 6);  // 0..15
    const int cg   = wv * 4;            // wave's co base (4 channels)
    const int pg0  = wv * 2;            // wave's co-pair base (2 pairs)
    const int noff = lane * 4;          // lane's n offset inside tile

    v2f acc[2][4];                      // [co-pair][n] packed over co
#pragma unroll
    for (int p = 0; p < 2; ++p)
#pragma unroll
        for (int j = 0; j < 4; ++j) acc[p][j] = v2f{0.0f, 0.0f};

    const float* xrow = x + (size_t)tb * C_ * N_;

    // lane's interior gload source offset (clamped only for n0==0, lane 0)
    int goff = n0 - PL_ + (lane << 2);
    if (goff < 0) goff = 0;

    // ---- prologue: stage chunk 0 into buffer 0 ----
    {
        const float* srow = xrow + (size_t)wv * N_;   // ci = wv
        __builtin_amdgcn_global_load_lds((const AS1 void*)(srow + goff),
                                         (AS3 void*)&xs[0][wv][0], 16, 0, 0);
        float tv = 0.0f, fv = 0.0f;
        if (lane < 7) {
            int n = n0 + 253 + lane;
            if (n < N_) tv = srow[n];
        }
        if (n0 == 0 && lane == 3) fv = srow[0];
        if (lane < 7) xs[0][wv][256 + lane] = tv;
        if (n0 == 0) {
            asm volatile("s_waitcnt vmcnt(0)" ::: "memory");
            if (lane < 4) xs[0][wv][lane] = (lane == 3) ? fv : 0.0f;
        }
    }
    __syncthreads();

    for (int cc = 0; cc < C_ / CCH_; ++cc) {
        const int b = cc & 1;

        // ---- issue stage of chunk cc+1 into the other buffer (async) ----
        float tv = 0.0f, fv = 0.0f;
        if (cc < 3) {
            const float* srown = xrow + (size_t)((cc + 1) * CCH_ + wv) * N_;
            __builtin_amdgcn_global_load_lds((const AS1 void*)(srown + goff),
                                             (AS3 void*)&xs[b ^ 1][wv][0], 16, 0, 0);
            if (lane < 7) {
                int n = n0 + 253 + lane;
                if (n < N_) tv = srown[n];
            }
            if (n0 == 0 && lane == 3) fv = srown[0];
        }

        // ---- compute chunk cc from xs[b] (R2 body, unrolled 4x) ----
#pragma unroll 4
        for (int ci2 = 0; ci2 < CCH_; ++ci2) {
            const int ci = cc * CCH_ + ci2;
            const float4* xp = (const float4*)(&xs[b][ci2][noff]);
            float4 xa = xp[0], xb = xp[1], xc = xp[2];
            float xr[12] = {xa.x, xa.y, xa.z, xa.w,
                            xb.x, xb.y, xb.z, xb.w,
                            xc.x, xc.y, xc.z, xc.w};
#pragma unroll
            for (int p = 0; p < 2; ++p) {
                // wave-uniform address -> s_load_dwordx2 (x4/x8 merged)
                const v2f* wq = wpk + ((size_t)(pg0 + p) * C_ + ci) * K_;
#pragma unroll
                for (int k = 0; k < K_; ++k) {
                    const v2f wv2 = wq[k];
#pragma unroll
                    for (int j = 0; j < 4; ++j) {
                        v2f xv = { xr[k + j], xr[k + j] };   // splat
                        acc[p][j] = __builtin_elementwise_fma(wv2, xv, acc[p][j]);
                    }
                }
            }
        }

        // ---- write-late tail + edge patch for the staged buffer ----
        if (cc < 3) {
            if (lane < 7) xs[b ^ 1][wv][256 + lane] = tv;
            if (n0 == 0) {
                asm volatile("s_waitcnt vmcnt(0)" ::: "memory");
                if (lane < 4) xs[b ^ 1][wv][lane] = (lane == 3) ? fv : 0.0f;
            }
            __syncthreads();   // gload drained (vmcnt0) + all waves done reading
        }
    }

    // write y + per-wave BN partials (deterministic: fixed reduction order,
    // identical per (co,bx) to the original version)
    float* yrow = y + (size_t)tb * CO_ * N_;
    const int nbase = n0 + noff;
#pragma unroll
    for (int p = 0; p < 2; ++p) {
        const int co0 = cg + 2 * p;
#pragma unroll
        for (int h = 0; h < 2; ++h) {
            float4 v;
            if (h == 0) v = make_float4(acc[p][0].x, acc[p][1].x, acc[p][2].x, acc[p][3].x);
            else        v = make_float4(acc[p][0].y, acc[p][1].y, acc[p][2].y, acc[p][3].y);
            const int co = co0 + h;
            *(float4*)(&yrow[(size_t)co * N_ + nbase]) = v;
            float s1 = (v.x + v.y) + (v.z + v.w);
            float s2 = (v.x * v.x + v.y * v.y) + (v.z * v.z + v.w * v.w);
#pragma unroll
            for (int off = 32; off > 0; off >>= 1) {
                s1 += __shfl_down(s1, off);
                s2 += __shfl_down(s2, off);
            }
            if (lane == 0) {
                psum[(size_t)(co * 2 + 0) * NBLK_ + bx] = s1;
                psum[(size_t)(co * 2 + 1) * NBLK_ + bx] = s2;
            }
        }
    }
}

// ---------------------------------------------------------------------------
// Kernel 2: per-channel BN stats (R3 verbatim) — 64 blocks, one per channel,
// bitwise-identical 256-thread strided loop + fp64 tree -> identical
// scale/shift. Writes into the dead wpk region.
// ---------------------------------------------------------------------------
__global__ __launch_bounds__(256)
void stats_kernel(const float* __restrict__ psum, const float* __restrict__ gamma,
                  const float* __restrict__ beta, float* __restrict__ ssf)
{
    __shared__ double red[256];

    const int c   = blockIdx.x;         // 0..63
    const int tid = threadIdx.x;

    double s1 = 0.0, s2 = 0.0;
    for (int i = tid; i < NBLK_; i += 256) {
        s1 += (double)psum[(size_t)(c * 2 + 0) * NBLK_ + i];
        s2 += (double)psum[(size_t)(c * 2 + 1) * NBLK_ + i];
    }
    red[tid] = s1;
    __syncthreads();
    for (int st = 128; st > 0; st >>= 1) {
        if (tid < st) red[tid] += red[tid + st];
        __syncthreads();
    }
    const double S1 = red[0];
    __syncthreads();
    red[tid] = s2;
    __syncthreads();
    for (int st = 128; st > 0; st >>= 1) {
        if (tid < st) red[tid] += red[tid + st];
        __syncthreads();
    }
    const double S2 = red[0];

    if (tid == 0) {
        const double M    = (double)TB_ * (double)N_;
        const double mean = S1 / M;
        const double var  = S2 / M - mean * mean;
        const double inv  = 1.0 / sqrt(var + 1e-5);
        const double g    = (double)gamma[c];
        ssf[2 * c + 0] = (float)(g * inv);
        ssf[2 * c + 1] = (float)((double)beta[c] - mean * g * inv);
    }
}

// ---------------------------------------------------------------------------
// Kernel 3: pure-streaming 4-step LIF (R3 verbatim). No LDS, no barriers;
// scale/shift block-uniform; 16 y4 loads issued up front; identical LIF
// arithmetic and nontemporal stores -> bitwise-identical spikes.
// ---------------------------------------------------------------------------
#define NQ4_   2097152     // B_*CO_*N_/4 : float4 elements per timestep
#define NTHR_  524288      // 2048 blocks * 256 threads

__global__ __launch_bounds__(256)
void lif_kernel(const float* __restrict__ y, const float* __restrict__ ssf,
                float* __restrict__ out)
{
    const int bx  = blockIdx.x;
    const int tid = threadIdx.x;
    const int c   = (bx >> 2) & 63;     // block-uniform channel

    const float scale = ssf[2 * c + 0];
    const float shift = ssf[2 * c + 1];

    const int f = bx * 256 + tid;
    const v4f* y4   = (const v4f*)y;
    v4f*       out4 = (v4f*)out;

    // issue all 16 loads first (grid covers NQ4_ exactly: 4 u-strides)
    v4f yv[4][4];
#pragma unroll
    for (int u = 0; u < 4; ++u)
#pragma unroll
        for (int t = 0; t < 4; ++t)
            yv[u][t] = y4[f + u * NTHR_ + t * NQ4_];

#pragma unroll
    for (int u = 0; u < 4; ++u) {
        float so[4][4];
#pragma unroll
        for (int e = 0; e < 4; ++e) {
            float v = 0.0f;
#pragma unroll
            for (int t = 0; t < 4; ++t) {
                const float yn = fmaf(yv[u][t][e], scale, shift);  // BN affine
                v = v + (yn - v) * 0.5f;                            // charge
                const float s = (v >= 1.0f) ? 1.0f : 0.0f;          // fire
                so[t][e] = s;
                v = (s != 0.0f) ? 0.0f : v;                         // hard reset
            }
        }
#pragma unroll
        for (int t = 0; t < 4; ++t) {
            v4f o = { so[t][0], so[t][1], so[t][2], so[t][3] };
            __builtin_nontemporal_store(o, &out4[f + u * NTHR_ + t * NQ4_]);
        }
    }
}

// ---------------------------------------------------------------------------
extern "C" void kernel_launch(void* const* d_in, const int* in_sizes, int n_in,
                              void* d_out, int out_size, void* d_ws, size_t ws_size,
                              hipStream_t stream)
{
    const float* x     = (const float*)d_in[0];   // [4,32,64,4096]
    const float* w     = (const float*)d_in[1];   // [64,64,8]
    // d_in[2] = conv_b: cancels in BN, unused
    const float* gamma = (const float*)d_in[3];   // [64]
    const float* beta  = (const float*)d_in[4];   // [64]
    float* out = (float*)d_out;

    char* ws = (char*)d_ws;
    const size_t y_bytes    = (size_t)TB_ * CO_ * N_ * sizeof(float);   // 128 MB
    const size_t psum_bytes = (size_t)CO_ * 2 * NBLK_ * sizeof(float);  // 1 MB
    float* y    = (float*)ws;
    float* psum = (float*)(ws + y_bytes);
    v2f*   wpk  = (v2f*)(ws + y_bytes + psum_bytes);
    float* ssf  = (float*)wpk;   // wpk region is dead after conv; reuse for 128 floats

    pack_w_kernel<<<64, 256, 0, stream>>>(w, wpk);
    conv_stats_kernel<<<NBLK_, 1024, 0, stream>>>(x, wpk, y, psum);
    stats_kernel<<<CO_, 256, 0, stream>>>(psum, gamma, beta, ssf);
    lif_kernel<<<NBLK_, 256, 0, stream>>>(y, ssf, out);
}

// Round 6
// 526.304 us; speedup vs baseline: 1.0075x; 1.0075x over previous
//
#include <hip/hip_runtime.h>
#include <math.h>

#define T_    4
#define B_    32
#define C_    64
#define CO_   64
#define N_    4096
#define K_    8
#define PL_   3
#define TB_   128          // T_*B_
#define TN_   256          // n-tile per conv block
#define NT_   16           // N_/TN_
#define NBLK_ 2048         // TB_*NT_
#define CCH_  32           // ci chunk staged in LDS. 32 here HALVES barrier count
                           // (4 -> 2 per block); safe now because LDS 2x33.8KB=67.6KB
                           // still allows 2 blocks/CU (waves bind, not LDS). The old
                           // CCH=32 regression was in the 256-thr register-staged
                           // structure where occupancy was LDS/VGPR-bound.

typedef float v2f __attribute__((ext_vector_type(2)));
typedef float v4f __attribute__((ext_vector_type(4)));

#define AS1 __attribute__((address_space(1)))
#define AS3 __attribute__((address_space(3)))

// ---------------------------------------------------------------------------
// Kernel 0: repack weights into co-pairs (R2 verbatim). Required: the packed
// conv codegen (wpk + pk-fma) eliminates LDS bank conflicts and ~40us of
// VALU time vs scalar-LDS weights.
// ---------------------------------------------------------------------------
__global__ __launch_bounds__(256)
void pack_w_kernel(const float* __restrict__ w, v2f* __restrict__ wpk)
{
    int i = blockIdx.x * 256 + threadIdx.x;      // p*512 + ci*8 + k
    if (i < 32 * C_ * K_) {
        int p = i >> 9;
        int r = i & 511;
        v2f v = { w[(size_t)(2 * p) * (C_ * K_) + r],
                  w[(size_t)(2 * p + 1) * (C_ * K_) + r] };
        wpk[i] = v;
    }
}

// ---------------------------------------------------------------------------
// Kernel 1: conv + BN partials. Staging structure as R2 (double-buffered xs +
// global_load_lds interior + T14 halo split), but CCH=32: 2 chunks instead of
// 4 -> 2 barriers per block instead of 4 (attacks the barrier-convoy share of
// the ~75us idle). Each wave stages 2 rows (wv, wv+16) per chunk. FMA order
// over ci is 0..63 ascending exactly as before -> y/psum bitwise identical.
// VGPR note: __launch_bounds__(1024,8) caps allocator at 64 VGPR — this is
// why unroll-based load pipelining can't materialize (R4/R5 lesson); do not
// expect VGPR to move.
// ---------------------------------------------------------------------------
__global__ __launch_bounds__(1024, 8)
void conv_stats_kernel(const float* __restrict__ x, const v2f* __restrict__ wpk,
                       float* __restrict__ y, float* __restrict__ psum)
{
    __shared__ float xs[2][CCH_][TN_ + 8];   // 2 x 32 x 264 floats = 67.6 KB

    const int bx   = blockIdx.x;
    const int tb   = bx >> 4;           // 0..127
    const int n0   = (bx & 15) * TN_;   // n tile origin
    const int tid  = threadIdx.x;
    const int lane = tid & 63;
    const int wv   = __builtin_amdgcn_readfirstlane(tid >> 6);  // 0..15
    const int cg   = wv * 4;            // wave's co base (4 channels)
    const int pg0  = wv * 2;            // wave's co-pair base (2 pairs)
    const int noff = lane * 4;          // lane's n offset inside tile

    v2f acc[2][4];                      // [co-pair][n] packed over co
#pragma unroll
    for (int p = 0; p < 2; ++p)
#pragma unroll
        for (int j = 0; j < 4; ++j) acc[p][j] = v2f{0.0f, 0.0f};

    const float* xrow = x + (size_t)tb * C_ * N_;

    // lane's interior gload source offset (clamped only for n0==0, lane 0)
    int goff = n0 - PL_ + (lane << 2);
    if (goff < 0) goff = 0;

    // ---- prologue: stage chunk 0 (rows 0..31) into buffer 0 ----
    {
        float fvs[2] = {0.0f, 0.0f};
#pragma unroll
        for (int rr = 0; rr < 2; ++rr) {
            const int r = rr * 16 + wv;               // ci = r
            const float* srow = xrow + (size_t)r * N_;
            __builtin_amdgcn_global_load_lds((const AS1 void*)(srow + goff),
                                             (AS3 void*)&xs[0][r][0], 16, 0, 0);
            float tv = 0.0f;
            if (lane < 7) {
                int n = n0 + 253 + lane;
                if (n < N_) tv = srow[n];
            }
            if (n0 == 0 && lane == 3) fvs[rr] = srow[0];
            if (lane < 7) xs[0][r][256 + lane] = tv;
        }
        if (n0 == 0) {
            asm volatile("s_waitcnt vmcnt(0)" ::: "memory");
#pragma unroll
            for (int rr = 0; rr < 2; ++rr) {
                const int r = rr * 16 + wv;
                if (lane < 4) xs[0][r][lane] = (lane == 3) ? fvs[rr] : 0.0f;
            }
        }
    }
    __syncthreads();

    for (int cc = 0; cc < C_ / CCH_; ++cc) {        // 2 chunks
        const int b = cc & 1;

        // ---- issue stage of chunk cc+1 (rows 32..63) into other buffer ----
        float tvs[2] = {0.0f, 0.0f}, fvs[2] = {0.0f, 0.0f};
        if (cc < 1) {
#pragma unroll
            for (int rr = 0; rr < 2; ++rr) {
                const int r = rr * 16 + wv;
                const float* srown = xrow + (size_t)(CCH_ + r) * N_;
                __builtin_amdgcn_global_load_lds((const AS1 void*)(srown + goff),
                                                 (AS3 void*)&xs[b ^ 1][r][0], 16, 0, 0);
                if (lane < 7) {
                    int n = n0 + 253 + lane;
                    if (n < N_) tvs[rr] = srown[n];
                }
                if (n0 == 0 && lane == 3) fvs[rr] = srown[0];
            }
        }

        // ---- compute chunk cc from xs[b] (verbatim body, 32 iters) ----
#pragma unroll 4
        for (int ci2 = 0; ci2 < CCH_; ++ci2) {
            const int ci = cc * CCH_ + ci2;
            const float4* xp = (const float4*)(&xs[b][ci2][noff]);
            float4 xa = xp[0], xb = xp[1], xc = xp[2];
            float xr[12] = {xa.x, xa.y, xa.z, xa.w,
                            xb.x, xb.y, xb.z, xb.w,
                            xc.x, xc.y, xc.z, xc.w};
#pragma unroll
            for (int p = 0; p < 2; ++p) {
                // wave-uniform address -> s_load_dwordx2 (x4/x8 merged)
                const v2f* wq = wpk + ((size_t)(pg0 + p) * C_ + ci) * K_;
#pragma unroll
                for (int k = 0; k < K_; ++k) {
                    const v2f wv2 = wq[k];
#pragma unroll
                    for (int j = 0; j < 4; ++j) {
                        v2f xv = { xr[k + j], xr[k + j] };   // splat
                        acc[p][j] = __builtin_elementwise_fma(wv2, xv, acc[p][j]);
                    }
                }
            }
        }

        // ---- write-late tail + edge patch for the staged buffer ----
        if (cc < 1) {
#pragma unroll
            for (int rr = 0; rr < 2; ++rr) {
                const int r = rr * 16 + wv;
                if (lane < 7) xs[b ^ 1][r][256 + lane] = tvs[rr];
            }
            if (n0 == 0) {
                asm volatile("s_waitcnt vmcnt(0)" ::: "memory");
#pragma unroll
                for (int rr = 0; rr < 2; ++rr) {
                    const int r = rr * 16 + wv;
                    if (lane < 4) xs[b ^ 1][r][lane] = (lane == 3) ? fvs[rr] : 0.0f;
                }
            }
            __syncthreads();   // gload drained (vmcnt0) + all waves done reading
        }
    }

    // write y + per-wave BN partials (deterministic: fixed reduction order,
    // identical per (co,bx) to the original version)
    float* yrow = y + (size_t)tb * CO_ * N_;
    const int nbase = n0 + noff;
#pragma unroll
    for (int p = 0; p < 2; ++p) {
        const int co0 = cg + 2 * p;
#pragma unroll
        for (int h = 0; h < 2; ++h) {
            float4 v;
            if (h == 0) v = make_float4(acc[p][0].x, acc[p][1].x, acc[p][2].x, acc[p][3].x);
            else        v = make_float4(acc[p][0].y, acc[p][1].y, acc[p][2].y, acc[p][3].y);
            const int co = co0 + h;
            *(float4*)(&yrow[(size_t)co * N_ + nbase]) = v;
            float s1 = (v.x + v.y) + (v.z + v.w);
            float s2 = (v.x * v.x + v.y * v.y) + (v.z * v.z + v.w * v.w);
#pragma unroll
            for (int off = 32; off > 0; off >>= 1) {
                s1 += __shfl_down(s1, off);
                s2 += __shfl_down(s2, off);
            }
            if (lane == 0) {
                psum[(size_t)(co * 2 + 0) * NBLK_ + bx] = s1;
                psum[(size_t)(co * 2 + 1) * NBLK_ + bx] = s2;
            }
        }
    }
}

// ---------------------------------------------------------------------------
// Kernel 2: per-channel BN stats (R3 verbatim) — 64 blocks, one per channel,
// bitwise-identical 256-thread strided loop + fp64 tree -> identical
// scale/shift. Writes into the dead wpk region.
// ---------------------------------------------------------------------------
__global__ __launch_bounds__(256)
void stats_kernel(const float* __restrict__ psum, const float* __restrict__ gamma,
                  const float* __restrict__ beta, float* __restrict__ ssf)
{
    __shared__ double red[256];

    const int c   = blockIdx.x;         // 0..63
    const int tid = threadIdx.x;

    double s1 = 0.0, s2 = 0.0;
    for (int i = tid; i < NBLK_; i += 256) {
        s1 += (double)psum[(size_t)(c * 2 + 0) * NBLK_ + i];
        s2 += (double)psum[(size_t)(c * 2 + 1) * NBLK_ + i];
    }
    red[tid] = s1;
    __syncthreads();
    for (int st = 128; st > 0; st >>= 1) {
        if (tid < st) red[tid] += red[tid + st];
        __syncthreads();
    }
    const double S1 = red[0];
    __syncthreads();
    red[tid] = s2;
    __syncthreads();
    for (int st = 128; st > 0; st >>= 1) {
        if (tid < st) red[tid] += red[tid + st];
        __syncthreads();
    }
    const double S2 = red[0];

    if (tid == 0) {
        const double M    = (double)TB_ * (double)N_;
        const double mean = S1 / M;
        const double var  = S2 / M - mean * mean;
        const double inv  = 1.0 / sqrt(var + 1e-5);
        const double g    = (double)gamma[c];
        ssf[2 * c + 0] = (float)(g * inv);
        ssf[2 * c + 1] = (float)((double)beta[c] - mean * g * inv);
    }
}

// ---------------------------------------------------------------------------
// Kernel 3: pure-streaming 4-step LIF (R3 verbatim). No LDS, no barriers;
// scale/shift block-uniform; 16 y4 loads issued up front; identical LIF
// arithmetic and nontemporal stores -> bitwise-identical spikes.
// ---------------------------------------------------------------------------
#define NQ4_   2097152     // B_*CO_*N_/4 : float4 elements per timestep
#define NTHR_  524288      // 2048 blocks * 256 threads

__global__ __launch_bounds__(256)
void lif_kernel(const float* __restrict__ y, const float* __restrict__ ssf,
                float* __restrict__ out)
{
    const int bx  = blockIdx.x;
    const int tid = threadIdx.x;
    const int c   = (bx >> 2) & 63;     // block-uniform channel

    const float scale = ssf[2 * c + 0];
    const float shift = ssf[2 * c + 1];

    const int f = bx * 256 + tid;
    const v4f* y4   = (const v4f*)y;
    v4f*       out4 = (v4f*)out;

    // issue all 16 loads first (grid covers NQ4_ exactly: 4 u-strides)
    v4f yv[4][4];
#pragma unroll
    for (int u = 0; u < 4; ++u)
#pragma unroll
        for (int t = 0; t < 4; ++t)
            yv[u][t] = y4[f + u * NTHR_ + t * NQ4_];

#pragma unroll
    for (int u = 0; u < 4; ++u) {
        float so[4][4];
#pragma unroll
        for (int e = 0; e < 4; ++e) {
            float v = 0.0f;
#pragma unroll
            for (int t = 0; t < 4; ++t) {
                const float yn = fmaf(yv[u][t][e], scale, shift);  // BN affine
                v = v + (yn - v) * 0.5f;                            // charge
                const float s = (v >= 1.0f) ? 1.0f : 0.0f;          // fire
                so[t][e] = s;
                v = (s != 0.0f) ? 0.0f : v;                         // hard reset
            }
        }
#pragma unroll
        for (int t = 0; t < 4; ++t) {
            v4f o = { so[t][0], so[t][1], so[t][2], so[t][3] };
            __builtin_nontemporal_store(o, &out4[f + u * NTHR_ + t * NQ4_]);
        }
    }
}

// ---------------------------------------------------------------------------
extern "C" void kernel_launch(void* const* d_in, const int* in_sizes, int n_in,
                              void* d_out, int out_size, void* d_ws, size_t ws_size,
                              hipStream_t stream)
{
    const float* x     = (const float*)d_in[0];   // [4,32,64,4096]
    const float* w     = (const float*)d_in[1];   // [64,64,8]
    // d_in[2] = conv_b: cancels in BN, unused
    const float* gamma = (const float*)d_in[3];   // [64]
    const float* beta  = (const float*)d_in[4];   // [64]
    float* out = (float*)d_out;

    char* ws = (char*)d_ws;
    const size_t y_bytes    = (size_t)TB_ * CO_ * N_ * sizeof(float);   // 128 MB
    const size_t psum_bytes = (size_t)CO_ * 2 * NBLK_ * sizeof(float);  // 1 MB
    float* y    = (float*)ws;
    float* psum = (float*)(ws + y_bytes);
    v2f*   wpk  = (v2f*)(ws + y_bytes + psum_bytes);
    float* ssf  = (float*)wpk;   // wpk region is dead after conv; reuse for 128 floats

    pack_w_kernel<<<64, 256, 0, stream>>>(w, wpk);
    conv_stats_kernel<<<NBLK_, 1024, 0, stream>>>(x, wpk, y, psum);
    stats_kernel<<<CO_, 256, 0, stream>>>(psum, gamma, beta, ssf);
    lif_kernel<<<NBLK_, 256, 0, stream>>>(y, ssf, out);
}

// Round 7
// 501.410 us; speedup vs baseline: 1.0575x; 1.0496x over previous
//
#include <hip/hip_runtime.h>
#include <math.h>

#define T_    4
#define B_    32
#define C_    64
#define CO_   64
#define N_    4096
#define K_    8
#define PL_   3
#define TB_   128          // T_*B_
#define TN_   256          // n-tile per conv block
#define NT_   16           // N_/TN_
#define NBLK_ 2048         // TB_*NT_
#define CCH_  16           // ci chunk staged in LDS (back to 16: 33.8KB dbuf -> 4 blocks/CU)

typedef float v2f __attribute__((ext_vector_type(2)));
typedef float v4f __attribute__((ext_vector_type(4)));

#define AS1 __attribute__((address_space(1)))
#define AS3 __attribute__((address_space(3)))

// ---------------------------------------------------------------------------
// Kernel 0: repack weights into co-pairs (R2 verbatim).
// ---------------------------------------------------------------------------
__global__ __launch_bounds__(256)
void pack_w_kernel(const float* __restrict__ w, v2f* __restrict__ wpk)
{
    int i = blockIdx.x * 256 + threadIdx.x;      // p*512 + ci*8 + k
    if (i < 32 * C_ * K_) {
        int p = i >> 9;
        int r = i & 511;
        v2f v = { w[(size_t)(2 * p) * (C_ * K_) + r],
                  w[(size_t)(2 * p + 1) * (C_ * K_) + r] };
        wpk[i] = v;
    }
}

// ---------------------------------------------------------------------------
// Kernel 1: conv + BN partials. THIS ROUND: LDS-reuse restructure.
// Model (R6): per ci2-round per CU, LDS wall (32 waves x 3 ds_read_b128 x
// 12cyc = 1152) slightly exceeded VALU wall (1056) -> LDS pipe bound; all
// VALU/sync levers were null (R1-R6). Fix: 8 waves x 8 co (was 16 x 4):
// same 48 B/lane LDS read now feeds 128 pk-FMA (2x reuse). New walls:
// VALU 2048 vs LDS 1152 -> VALU-bound with 44% slack.
// Staging structure R2-frozen (dbuf + global_load_lds + T14 halo split,
// 1 barrier/chunk); each of 8 waves stages 2 rows {wv, wv+8} per chunk.
// FMA order per output (ci 0..63, k 0..7), lane->n map, shuffle reduce
// unchanged -> y/psum bitwise identical.
// launch_bounds(512,6): don't strangle allocator at 64 VGPR (R4/R5 lesson);
// 4-6 waves/SIMD proved sufficient (R0/R1).
// ---------------------------------------------------------------------------
__global__ __launch_bounds__(512, 6)
void conv_stats_kernel(const float* __restrict__ x, const v2f* __restrict__ wpk,
                       float* __restrict__ y, float* __restrict__ psum)
{
    __shared__ float xs[2][CCH_][TN_ + 8];   // 2 x 16 x 264 floats = 33.8 KB

    const int bx   = blockIdx.x;
    const int tb   = bx >> 4;           // 0..127
    const int n0   = (bx & 15) * TN_;   // n tile origin
    const int tid  = threadIdx.x;
    const int lane = tid & 63;
    const int wv   = __builtin_amdgcn_readfirstlane(tid >> 6);  // 0..7
    const int cg   = wv * 8;            // wave's co base (8 channels)
    const int pg0  = wv * 4;            // wave's co-pair base (4 pairs)
    const int noff = lane * 4;          // lane's n offset inside tile

    v2f acc[4][4];                      // [co-pair][n] packed over co
#pragma unroll
    for (int p = 0; p < 4; ++p)
#pragma unroll
        for (int j = 0; j < 4; ++j) acc[p][j] = v2f{0.0f, 0.0f};

    const float* xrow = x + (size_t)tb * C_ * N_;

    // lane's interior gload source offset (clamped only for n0==0, lane 0)
    int goff = n0 - PL_ + (lane << 2);
    if (goff < 0) goff = 0;

    // ---- prologue: stage chunk 0 (rows 0..15) into buffer 0 ----
    {
        float fvs[2] = {0.0f, 0.0f};
#pragma unroll
        for (int rr = 0; rr < 2; ++rr) {
            const int r = rr * 8 + wv;                // ci = r
            const float* srow = xrow + (size_t)r * N_;
            __builtin_amdgcn_global_load_lds((const AS1 void*)(srow + goff),
                                             (AS3 void*)&xs[0][r][0], 16, 0, 0);
            float tv = 0.0f;
            if (lane < 7) {
                int n = n0 + 253 + lane;
                if (n < N_) tv = srow[n];
            }
            if (n0 == 0 && lane == 3) fvs[rr] = srow[0];
            if (lane < 7) xs[0][r][256 + lane] = tv;
        }
        if (n0 == 0) {
            asm volatile("s_waitcnt vmcnt(0)" ::: "memory");
#pragma unroll
            for (int rr = 0; rr < 2; ++rr) {
                const int r = rr * 8 + wv;
                if (lane < 4) xs[0][r][lane] = (lane == 3) ? fvs[rr] : 0.0f;
            }
        }
    }
    __syncthreads();

    for (int cc = 0; cc < C_ / CCH_; ++cc) {        // 4 chunks
        const int b = cc & 1;

        // ---- issue stage of chunk cc+1 into the other buffer (async) ----
        float tvs[2] = {0.0f, 0.0f}, fvs[2] = {0.0f, 0.0f};
        if (cc < 3) {
#pragma unroll
            for (int rr = 0; rr < 2; ++rr) {
                const int r = rr * 8 + wv;
                const float* srown = xrow + (size_t)((cc + 1) * CCH_ + r) * N_;
                __builtin_amdgcn_global_load_lds((const AS1 void*)(srown + goff),
                                                 (AS3 void*)&xs[b ^ 1][r][0], 16, 0, 0);
                if (lane < 7) {
                    int n = n0 + 253 + lane;
                    if (n < N_) tvs[rr] = srown[n];
                }
                if (n0 == 0 && lane == 3) fvs[rr] = srown[0];
            }
        }

        // ---- compute chunk cc from xs[b]: 3 ds_read_b128 -> 128 pk-fma ----
        for (int ci2 = 0; ci2 < CCH_; ++ci2) {
            const int ci = cc * CCH_ + ci2;
            const float4* xp = (const float4*)(&xs[b][ci2][noff]);
            float4 xa = xp[0], xb = xp[1], xc = xp[2];
            float xr[12] = {xa.x, xa.y, xa.z, xa.w,
                            xb.x, xb.y, xb.z, xb.w,
                            xc.x, xc.y, xc.z, xc.w};
#pragma unroll
            for (int p = 0; p < 4; ++p) {
                // wave-uniform address -> s_load_dwordx2 (x4/x8 merged)
                const v2f* wq = wpk + ((size_t)(pg0 + p) * C_ + ci) * K_;
#pragma unroll
                for (int k = 0; k < K_; ++k) {
                    const v2f wv2 = wq[k];
#pragma unroll
                    for (int j = 0; j < 4; ++j) {
                        v2f xv = { xr[k + j], xr[k + j] };   // splat
                        acc[p][j] = __builtin_elementwise_fma(wv2, xv, acc[p][j]);
                    }
                }
            }
        }

        // ---- write-late tail + edge patch for the staged buffer ----
        if (cc < 3) {
#pragma unroll
            for (int rr = 0; rr < 2; ++rr) {
                const int r = rr * 8 + wv;
                if (lane < 7) xs[b ^ 1][r][256 + lane] = tvs[rr];
            }
            if (n0 == 0) {
                asm volatile("s_waitcnt vmcnt(0)" ::: "memory");
#pragma unroll
                for (int rr = 0; rr < 2; ++rr) {
                    const int r = rr * 8 + wv;
                    if (lane < 4) xs[b ^ 1][r][lane] = (lane == 3) ? fvs[rr] : 0.0f;
                }
            }
            __syncthreads();   // gload drained (vmcnt0) + all waves done reading
        }
    }

    // write y + per-wave BN partials (deterministic: fixed reduction order,
    // identical values per (co,bx) to previous rounds)
    float* yrow = y + (size_t)tb * CO_ * N_;
    const int nbase = n0 + noff;
#pragma unroll
    for (int p = 0; p < 4; ++p) {
        const int co0 = cg + 2 * p;
#pragma unroll
        for (int h = 0; h < 2; ++h) {
            float4 v;
            if (h == 0) v = make_float4(acc[p][0].x, acc[p][1].x, acc[p][2].x, acc[p][3].x);
            else        v = make_float4(acc[p][0].y, acc[p][1].y, acc[p][2].y, acc[p][3].y);
            const int co = co0 + h;
            *(float4*)(&yrow[(size_t)co * N_ + nbase]) = v;
            float s1 = (v.x + v.y) + (v.z + v.w);
            float s2 = (v.x * v.x + v.y * v.y) + (v.z * v.z + v.w * v.w);
#pragma unroll
            for (int off = 32; off > 0; off >>= 1) {
                s1 += __shfl_down(s1, off);
                s2 += __shfl_down(s2, off);
            }
            if (lane == 0) {
                psum[(size_t)(co * 2 + 0) * NBLK_ + bx] = s1;
                psum[(size_t)(co * 2 + 1) * NBLK_ + bx] = s2;
            }
        }
    }
}

// ---------------------------------------------------------------------------
// Kernel 2: per-channel BN stats (R3 verbatim) — 64 blocks, one per channel,
// bitwise-identical strided loop + fp64 tree -> identical scale/shift.
// ---------------------------------------------------------------------------
__global__ __launch_bounds__(256)
void stats_kernel(const float* __restrict__ psum, const float* __restrict__ gamma,
                  const float* __restrict__ beta, float* __restrict__ ssf)
{
    __shared__ double red[256];

    const int c   = blockIdx.x;         // 0..63
    const int tid = threadIdx.x;

    double s1 = 0.0, s2 = 0.0;
    for (int i = tid; i < NBLK_; i += 256) {
        s1 += (double)psum[(size_t)(c * 2 + 0) * NBLK_ + i];
        s2 += (double)psum[(size_t)(c * 2 + 1) * NBLK_ + i];
    }
    red[tid] = s1;
    __syncthreads();
    for (int st = 128; st > 0; st >>= 1) {
        if (tid < st) red[tid] += red[tid + st];
        __syncthreads();
    }
    const double S1 = red[0];
    __syncthreads();
    red[tid] = s2;
    __syncthreads();
    for (int st = 128; st > 0; st >>= 1) {
        if (tid < st) red[tid] += red[tid + st];
        __syncthreads();
    }
    const double S2 = red[0];

    if (tid == 0) {
        const double M    = (double)TB_ * (double)N_;
        const double mean = S1 / M;
        const double var  = S2 / M - mean * mean;
        const double inv  = 1.0 / sqrt(var + 1e-5);
        const double g    = (double)gamma[c];
        ssf[2 * c + 0] = (float)(g * inv);
        ssf[2 * c + 1] = (float)((double)beta[c] - mean * g * inv);
    }
}

// ---------------------------------------------------------------------------
// Kernel 3: pure-streaming 4-step LIF (R3 verbatim).
// ---------------------------------------------------------------------------
#define NQ4_   2097152     // B_*CO_*N_/4 : float4 elements per timestep
#define NTHR_  524288      // 2048 blocks * 256 threads

__global__ __launch_bounds__(256)
void lif_kernel(const float* __restrict__ y, const float* __restrict__ ssf,
                float* __restrict__ out)
{
    const int bx  = blockIdx.x;
    const int tid = threadIdx.x;
    const int c   = (bx >> 2) & 63;     // block-uniform channel

    const float scale = ssf[2 * c + 0];
    const float shift = ssf[2 * c + 1];

    const int f = bx * 256 + tid;
    const v4f* y4   = (const v4f*)y;
    v4f*       out4 = (v4f*)out;

    // issue all 16 loads first (grid covers NQ4_ exactly: 4 u-strides)
    v4f yv[4][4];
#pragma unroll
    for (int u = 0; u < 4; ++u)
#pragma unroll
        for (int t = 0; t < 4; ++t)
            yv[u][t] = y4[f + u * NTHR_ + t * NQ4_];

#pragma unroll
    for (int u = 0; u < 4; ++u) {
        float so[4][4];
#pragma unroll
        for (int e = 0; e < 4; ++e) {
            float v = 0.0f;
#pragma unroll
            for (int t = 0; t < 4; ++t) {
                const float yn = fmaf(yv[u][t][e], scale, shift);  // BN affine
                v = v + (yn - v) * 0.5f;                            // charge
                const float s = (v >= 1.0f) ? 1.0f : 0.0f;          // fire
                so[t][e] = s;
                v = (s != 0.0f) ? 0.0f : v;                         // hard reset
            }
        }
#pragma unroll
        for (int t = 0; t < 4; ++t) {
            v4f o = { so[t][0], so[t][1], so[t][2], so[t][3] };
            __builtin_nontemporal_store(o, &out4[f + u * NTHR_ + t * NQ4_]);
        }
    }
}

// ---------------------------------------------------------------------------
extern "C" void kernel_launch(void* const* d_in, const int* in_sizes, int n_in,
                              void* d_out, int out_size, void* d_ws, size_t ws_size,
                              hipStream_t stream)
{
    const float* x     = (const float*)d_in[0];   // [4,32,64,4096]
    const float* w     = (const float*)d_in[1];   // [64,64,8]
    // d_in[2] = conv_b: cancels in BN, unused
    const float* gamma = (const float*)d_in[3];   // [64]
    const float* beta  = (const float*)d_in[4];   // [64]
    float* out = (float*)d_out;

    char* ws = (char*)d_ws;
    const size_t y_bytes    = (size_t)TB_ * CO_ * N_ * sizeof(float);   // 128 MB
    const size_t psum_bytes = (size_t)CO_ * 2 * NBLK_ * sizeof(float);  // 1 MB
    float* y    = (float*)ws;
    float* psum = (float*)(ws + y_bytes);
    v2f*   wpk  = (v2f*)(ws + y_bytes + psum_bytes);
    float* ssf  = (float*)wpk;   // wpk region is dead after conv; reuse for 128 floats

    pack_w_kernel<<<64, 256, 0, stream>>>(w, wpk);
    conv_stats_kernel<<<NBLK_, 512, 0, stream>>>(x, wpk, y, psum);
    stats_kernel<<<CO_, 256, 0, stream>>>(psum, gamma, beta, ssf);
    lif_kernel<<<NBLK_, 256, 0, stream>>>(y, ssf, out);
}